// Round 6
// baseline (11268.006 us; speedup 1.0000x reference)
//
#include <hip/hip_runtime.h>

// ZoneoutGRU persistent kernel v13 = v12 + MEASUREMENT PROBE. B=64, T=1024,
// IN=512, H=1024, L=2, zo=0.1. 128 active blocks (64 LA, 64 LB), 256 thr.
// v12 protocol (mailbox, private reader rows) byte-identical; ADDED: one
// DUMMY flag hop per step (mailbox groups 4=LA, 5=LB), same structure as the
// real hop (64-lane scatter store -> 64-lane gather poll), strictly serial
// after the real fan-out. Purpose: hop_sync = (dur_v13 - dur_v12)/1024
// decomposes the ~10.4us step period into sync-hop vs drain/fill/compute.
// Ledger of falsified theories: DVFS (v8), poll congestion (v9), load depth
// (v10), chain order/fusion (v11), reader-line contention (v12). New v12
// evidence: scattered 4B/8B agent stores cost full 64B lines (WRITE_SIZE
// +1MB/step for the 128-store fan-out); ring reads fill from MALL/HBM
// (FETCH ~1.8MB/step ~= ring volume).

#define Tn 1024
#define Hn 1024
#define INn 512

typedef short s8v __attribute__((ext_vector_type(8)));
typedef float f4v __attribute__((ext_vector_type(4)));
typedef unsigned short us4v __attribute__((ext_vector_type(4)));
typedef unsigned long long ull;

// ws layout (bytes)
#define WS_XB  0u           // x bf16 [64][1024][512]            = 67,108,864
#define WS_H0R 67108864u    // ring [512][ktile64][b64][16] bf16 = 67,108,864
#define WS_H1R 134217728u   // ring [256][ktile64][b64][16] bf16 = 33,554,432
#define WS_MB  167772160u   // mailbox [8][64][64] int           =    131,072

__device__ __forceinline__ unsigned short f2bf(float f) {
  unsigned int u = __float_as_uint(f);
  u += 0x7fffu + ((u >> 16) & 1u);
  return (unsigned short)(u >> 16);
}

__device__ __forceinline__ s8v pack8(const float* p) {
  float4 a = *(const float4*)p;
  float4 b = *(const float4*)(p + 4);
  s8v r;
  r[0] = (short)f2bf(a.x); r[1] = (short)f2bf(a.y);
  r[2] = (short)f2bf(a.z); r[3] = (short)f2bf(a.w);
  r[4] = (short)f2bf(b.x); r[5] = (short)f2bf(b.y);
  r[6] = (short)f2bf(b.z); r[7] = (short)f2bf(b.w);
  return r;
}

// producer store: relaxed agent-scope 8B atomic = write-through to MALL (v3+)
__device__ __forceinline__ void st8c(unsigned short* p, us4v v) {
  union { us4v v; ull u; } c; c.v = v;
  __hip_atomic_store((ull*)p, c.u, __ATOMIC_RELAXED, __HIP_MEMORY_SCOPE_AGENT);
}

// nt store via asm: ordered against other asm/memory ops (drain-count safety)
__device__ __forceinline__ void stnt16(float* p, f4v v) {
  asm volatile("global_store_dwordx4 %0, %1, off nt" :: "v"(p), "v"(v) : "memory");
}

// consumer loads: sc0 only — L1-bypass, L2-CACHEABLE (deep ring => no stale)
__device__ __forceinline__ void issue4c(s8v* f, const unsigned short* src,
                                        int kt, int w, int rl, int kg) {
#pragma unroll
  for (int m = 0; m < 4; ++m) {
    const unsigned short* p = src + (size_t)(w * 16 + kt * 2 + (kg >> 1)) * 1024
                              + (m * 16 + rl) * 16 + (kg & 1) * 8;
    asm volatile("global_load_dwordx4 %0, %1, off sc0"
                 : "=v"(f[m]) : "v"(p) : "memory");
  }
}

template<int N> __device__ __forceinline__ void vmwait() {
  asm volatile("s_waitcnt vmcnt(%0)" :: "i"(N) : "memory");
  __builtin_amdgcn_sched_barrier(0);
}

__device__ __forceinline__ void mfma3(f4v (*acc)[4], s8v w0, s8v w1, s8v w2,
                                      const s8v f[4], const int gl) {
#pragma unroll
  for (int m = 0; m < 4; ++m) {
    acc[m][0]  = __builtin_amdgcn_mfma_f32_16x16x32_bf16(w0, f[m], acc[m][0], 0, 0, 0);
    acc[m][1]  = __builtin_amdgcn_mfma_f32_16x16x32_bf16(w1, f[m], acc[m][1], 0, 0, 0);
    acc[m][gl] = __builtin_amdgcn_mfma_f32_16x16x32_bf16(w2, f[m], acc[m][gl], 0, 0, 0);
  }
}

// v10 deep-pipelined stream GEMM: pre-issue 24 loads (depth-6 fragment ring),
// consume with descending counted vmcnt, re-issue after consume (WAR-safe).
// Precondition: vmcnt == 0 on entry; self-drains on exit.
template<int GL>
__device__ __forceinline__ void stream_gemm_deep(f4v (*acc)[4], const s8v (*wgt)[8],
    const unsigned short* src, int w, int rl, int kg) {
  s8v f[6][4];
#pragma unroll
  for (int kt = 0; kt < 6; ++kt) issue4c(f[kt], src, kt, w, rl, kg);
  vmwait<20>(); mfma3(acc, wgt[0][0], wgt[1][0], wgt[2][0], f[0], GL);
  issue4c(f[0], src, 6, w, rl, kg);
  vmwait<20>(); mfma3(acc, wgt[0][1], wgt[1][1], wgt[2][1], f[1], GL);
  issue4c(f[1], src, 7, w, rl, kg);
  vmwait<20>(); mfma3(acc, wgt[0][2], wgt[1][2], wgt[2][2], f[2], GL);
  vmwait<16>(); mfma3(acc, wgt[0][3], wgt[1][3], wgt[2][3], f[3], GL);
  vmwait<12>(); mfma3(acc, wgt[0][4], wgt[1][4], wgt[2][4], f[4], GL);
  vmwait<8>();  mfma3(acc, wgt[0][5], wgt[1][5], wgt[2][5], f[5], GL);
  vmwait<4>();  mfma3(acc, wgt[0][6], wgt[1][6], wgt[2][6], f[0], GL);
  vmwait<0>();  mfma3(acc, wgt[0][7], wgt[1][7], wgt[2][7], f[1], GL);
}

__global__ void cvt_bf16_kernel(const float* __restrict__ src,
                                unsigned short* __restrict__ dst, int n4) {
  int i = blockIdx.x * blockDim.x + threadIdx.x;
  int st = gridDim.x * blockDim.x;
  for (; i < n4; i += st) {
    const float4 v = *(const float4*)(src + 4 * (size_t)i);
    us4v o;
    o[0] = f2bf(v.x); o[1] = f2bf(v.y); o[2] = f2bf(v.z); o[3] = f2bf(v.w);
    *(us4v*)(dst + 4 * (size_t)i) = o;
  }
}

__global__ void init_all(const float* __restrict__ h0in, char* __restrict__ ws) {
  int i = blockIdx.x * blockDim.x + threadIdx.x;   // grid 528*256 = 135168
  unsigned short* h0r = (unsigned short*)(ws + WS_H0R);
  unsigned short* h1r = (unsigned short*)(ws + WS_H1R);
  int* MB = (int*)(ws + WS_MB);
  if (i < 65536) {
    int b = i >> 10, h = i & 1023;
    int off = (h >> 4) * 1024 + b * 16 + (h & 15);
    h0r[511 * 65536 + off] = f2bf(h0in[i]);          // slot for step -1
    h1r[255 * 65536 + off] = f2bf(h0in[65536 + i]);  // slot for step -1
  }
  if (i < 32768) MB[i] = 0;                          // all 8 mailbox groups: 0
}

// consumer wait: 64-lane gather over this block's PRIVATE mailbox rows
// (sole reader per line). row index = grp*64 + consumer; lane = producer.
__device__ __forceinline__ void mb_wait(const int* MB, int r1, int t1,
                                        int r2, int t2, int lane) {
  const int* p1 = MB + (r1 * 64 + lane);
  const int* p2 = MB + (r2 * 64 + lane);
  int tries = 0;
  for (;;) {
    int v1 = __hip_atomic_load(p1, __ATOMIC_RELAXED, __HIP_MEMORY_SCOPE_AGENT);
    int v2 = __hip_atomic_load(p2, __ATOMIC_RELAXED, __HIP_MEMORY_SCOPE_AGENT);
    if (__all(v1 >= t1 && v2 >= t2)) return;
    __builtin_amdgcn_s_sleep(1);
    if (++tries > (1 << 22)) return;   // fail visibly, never hang
  }
}

__global__ __launch_bounds__(256, 1) void gru_persist(
    const float* __restrict__ h0in,
    const float* __restrict__ wih0, const float* __restrict__ whh0,
    const float* __restrict__ bih0, const float* __restrict__ bhh0,
    const float* __restrict__ wih1, const float* __restrict__ whh1,
    const float* __restrict__ bih1, const float* __restrict__ bhh1,
    float* __restrict__ out, char* __restrict__ ws)
{
  const unsigned short* xb = (const unsigned short*)(ws + WS_XB);
  unsigned short* h0r = (unsigned short*)(ws + WS_H0R);
  unsigned short* h1r = (unsigned short*)(ws + WS_H1R);
  int* MB = (int*)(ws + WS_MB);

  const int blk = blockIdx.x;
  const int tid = threadIdx.x;

  if (blk >= 128) {
    // busy-clock pad (insurance): NO LDS, NO barriers — each wave polls its
    // block's grp2 mailbox row every ~33k cy; exits when all LB steps done.
    const int c = blk & 63;
    float a0 = 1.0f + (float)tid * 1e-6f, a1 = a0 + 0.25f;
    float a2 = a0 + 0.5f, a3 = a0 + 0.75f;
    const float mm = 0.99999988f, cc = 1e-7f;
    int run = 1;
    for (int it = 0; it < (1 << 17) && run; ++it) {
#pragma unroll
      for (int u = 0; u < 256; ++u) {
        a0 = __builtin_fmaf(a0, mm, cc); a1 = __builtin_fmaf(a1, mm, cc);
        a2 = __builtin_fmaf(a2, mm, cc); a3 = __builtin_fmaf(a3, mm, cc);
      }
      if ((it & 15) == 0) {
        int v = __hip_atomic_load(MB + (((2 * 64) + c) * 64 + (tid & 63)),
                                  __ATOMIC_RELAXED, __HIP_MEMORY_SCOPE_AGENT);
        if (__all(v >= Tn)) run = 0;
      }
    }
    asm volatile("" :: "v"(a0), "v"(a1), "v"(a2), "v"(a3));  // keep chains live
    return;
  }

  const bool isA = blk < 64;
  const int jt = blk & 63, jj = jt * 16;
  const int w = tid >> 6;                    // wave = K-slice = owner m-group
  const int lane = tid & 63;
  const int rl = lane & 15, kg = lane >> 4;

  __shared__ float cmb[4][4][64][20];        // stride 80B: conflict-free (r6)

  const int b = w * 16 + rl;                 // owner batch row (epilogue)
  const int j0 = jj + kg * 4;                // owner j base (epilogue)

  // ---- VGPR-resident weights ----
  const float* Wi = isA ? wih0 : wih1;
  const float* Wh = isA ? whh0 : whh1;
  const float* bi = isA ? bih0 : bih1;
  const float* bh = isA ? bhh0 : bhh1;
  const int Kx = isA ? INn : Hn;             // input-side K
  s8v wx[3][8], wh_[3][8];
  const int nkx = Kx / 128;                  // 4 (LA) or 8 (LB) k-tiles of 32
#pragma unroll
  for (int g = 0; g < 3; ++g) {
    for (int kt = 0; kt < nkx; ++kt)
      wx[g][kt] = pack8(Wi + (size_t)(g * 1024 + jj + rl) * Kx + w * (Kx / 4) + kt * 32 + kg * 8);
#pragma unroll
    for (int kt = 0; kt < 8; ++kt)
      wh_[g][kt] = pack8(Wh + (size_t)(g * 1024 + jj + rl) * Hn + w * 256 + kt * 32 + kg * 8);
  }
  const f4v bir = *(const f4v*)(bi + j0),        bhr = *(const f4v*)(bh + j0);
  const f4v biz = *(const f4v*)(bi + 1024 + j0), bhz = *(const f4v*)(bh + 1024 + j0);
  const f4v bin = *(const f4v*)(bi + 2048 + j0), bhn = *(const f4v*)(bh + 2048 + j0);

  // ---- register-resident fp32 hidden state (this thread's (b, j0..j0+3)) ----
  f4v hv = *(const f4v*)(h0in + (isA ? 0u : 65536u) + (size_t)b * Hn + j0);

  for (int s = 0; s < Tn; ++s) {
    // 1. LA: prefetch x fragments (plain cached loads, v4-proven) before spin
    s8v bx[4][4];
    if (isA) {
#pragma unroll
      for (int m = 0; m < 4; ++m)
#pragma unroll
        for (int kt = 0; kt < 4; ++kt)
          bx[m][kt] = *(const s8v*)(xb + ((size_t)(m * 16 + rl) * Tn + s) * INn + w * 128 + kt * 32 + kg * 8);
    }
    // 2. mailbox wait (wave0 only; private rows, sole reader per line)
    if (w == 0) {
      if (isA) mb_wait(MB, 0 * 64 + jt, s,     3 * 64 + jt, s - 255, lane);
      else     mb_wait(MB, 1 * 64 + jt, s + 1, 2 * 64 + jt, s,       lane);
    }
    __syncthreads();
    vmwait<0>();                             // clean baseline for counted pipe

    f4v acc[4][4];
#pragma unroll
    for (int m = 0; m < 4; ++m)
#pragma unroll
      for (int g = 0; g < 4; ++g) acc[m][g] = (f4v){0.f, 0.f, 0.f, 0.f};

    // deep-ring slots (no address reuse within 256+ steps => L2-cache safe)
    const unsigned short* hsrc = isA ? (h0r + (size_t)((s - 1) & 511) * 65536)
                                     : (h1r + (size_t)((s - 1) & 255) * 65536);
    const unsigned short* asrc = h0r + (size_t)(s & 511) * 65536;  // LB input h0[s]

    if (isA) {
      // 3a. x-GEMM from registers
#pragma unroll
      for (int kt = 0; kt < 4; ++kt) {
        s8v f4[4] = { bx[0][kt], bx[1][kt], bx[2][kt], bx[3][kt] };
        mfma3(acc, wx[0][kt], wx[1][kt], wx[2][kt], f4, 2);
      }
      // 3b. hidden stream, deep-pipelined (~1 exposed RTT)
      stream_gemm_deep<3>(acc, wh_, hsrc, w, rl, kg);
    } else {
      // 3. a-stream then h-stream, each deep-pipelined (self-draining)
      stream_gemm_deep<2>(acc, wx, asrc, w, rl, kg);
      stream_gemm_deep<3>(acc, wh_, hsrc, w, rl, kg);
    }

    // 4. cross-wave K-combine (LDS)
#pragma unroll
    for (int d = 0; d < 4; ++d) if (d != w)
#pragma unroll
      for (int g = 0; g < 4; ++g) *(f4v*)&cmb[d][w][lane][g * 4] = acc[d][g];
    __syncthreads();
    f4v hsum[4];
#pragma unroll
    for (int g = 0; g < 4; ++g) {
      hsum[g] = acc[w][g];
#pragma unroll
      for (int src = 0; src < 4; ++src) if (src != w) hsum[g] += *(f4v*)&cmb[w][src][lane][g * 4];
    }

    // 5. epilogue: gates + zoneout, state stays in hv registers
    us4v hb4;
#pragma unroll
    for (int rr = 0; rr < 4; ++rr) {
      float hp = hv[rr];
      float rg = 1.f / (1.f + __expf(-(hsum[0][rr] + bir[rr] + bhr[rr])));
      float zg = 1.f / (1.f + __expf(-(hsum[1][rr] + biz[rr] + bhz[rr])));
      float narg = hsum[2][rr] + bin[rr] + rg * (hsum[3][rr] + bhn[rr]);
      float e2 = __expf(2.f * narg);
      float ng = 1.f - 2.f / (e2 + 1.f);
      float nv = (1.f - zg) * ng + zg * hp;
      hv[rr] = 0.1f * hp + 0.9f * nv;
    }
    hb4[0] = f2bf(hv[0]); hb4[1] = f2bf(hv[1]); hb4[2] = f2bf(hv[2]); hb4[3] = f2bf(hv[3]);

    // 6. broadcast bf16 h (write-through 8B atomics, issued FIRST), then out
    //    nt-stores; counted drain: wait only until st8c is acked.
    if (isA) {
      st8c(h0r + (size_t)(s & 511) * 65536 + jt * 1024 + b * 16 + kg * 4, hb4);
      if (s == Tn - 1)
        stnt16(out + 67108864u + (size_t)b * Hn + j0, hv);
      vmwait<0>();                           // st8c (+final store) acked
    } else {
      st8c(h1r + (size_t)(s & 255) * 65536 + jt * 1024 + b * 16 + kg * 4, hb4);
      stnt16(out + ((size_t)b * Tn + s) * Hn + j0, hv);
      if (s == Tn - 1) {
        stnt16(out + 67108864u + 65536u + (size_t)b * Hn + j0, hv);
        vmwait<0>();
      } else {
        vmwait<1>();                         // st8c acked; out-store off-chain
      }
    }
    __syncthreads();
    // 7. real flag fan-out: wave0's 64 lanes scatter (s+1) to the 64
    //    consumer rows of each served group (plain relaxed stores, no RMW).
    if (tid < 64) {
      const int g1 = isA ? 0 : 2, g2 = isA ? 1 : 3;
      __hip_atomic_store(MB + ((g1 * 64 + tid) * 64 + jt), s + 1,
                         __ATOMIC_RELAXED, __HIP_MEMORY_SCOPE_AGENT);
      __hip_atomic_store(MB + ((g2 * 64 + tid) * 64 + jt), s + 1,
                         __ATOMIC_RELAXED, __HIP_MEMORY_SCOPE_AGENT);
    }
    // 8. ===== PROBE: dummy extra hop, strictly serial =====
    //    Fan-out (s+1) on grp4 (LA) / grp5 (LB), then wait for ALL 64
    //    producers of this layer group at (s+1) on own dummy row.
    //    Deadlock-free: every block stores before waiting; real protocol
    //    guarantees all siblings reach this point for step s.
    {
      const int gd = isA ? 4 : 5;
      if (tid < 64)
        __hip_atomic_store(MB + ((gd * 64 + tid) * 64 + jt), s + 1,
                           __ATOMIC_RELAXED, __HIP_MEMORY_SCOPE_AGENT);
      if (w == 0)
        mb_wait(MB, gd * 64 + jt, s + 1, gd * 64 + jt, s + 1, lane);
      __syncthreads();
    }
  }
}

extern "C" void kernel_launch(void* const* d_in, const int* in_sizes, int n_in,
                              void* d_out, int out_size, void* d_ws, size_t ws_size,
                              hipStream_t stream) {
  (void)in_sizes; (void)n_in; (void)out_size; (void)ws_size;
  const float* x    = (const float*)d_in[0];
  const float* h0in = (const float*)d_in[1];
  const float* wih0 = (const float*)d_in[2];
  const float* whh0 = (const float*)d_in[3];
  const float* bih0 = (const float*)d_in[4];
  const float* bhh0 = (const float*)d_in[5];
  const float* wih1 = (const float*)d_in[6];
  const float* whh1 = (const float*)d_in[7];
  const float* bih1 = (const float*)d_in[8];
  const float* bhh1 = (const float*)d_in[9];
  float* out = (float*)d_out;
  char* ws = (char*)d_ws;

  cvt_bf16_kernel<<<2048, 256, 0, stream>>>(x, (unsigned short*)(ws + WS_XB), 33554432 / 4);
  init_all<<<528, 256, 0, stream>>>(h0in, ws);
  gru_persist<<<dim3(256), dim3(256), 0, stream>>>(
      h0in, wih0, whh0, bih0, bhh0, wih1, whh1, bih1, bhh1, out, ws);
}

// Round 7
// 10587.190 us; speedup vs baseline: 1.0643x; 1.0643x over previous
//
#include <hip/hip_runtime.h>

// ZoneoutGRU persistent kernel v14: B=64, T=1024, IN=512, H=1024, L=2, zo=0.1.
// 128 active blocks (64 LA = layer0, 64 LB = layer1), 256 thr (4 waves = K
// slices). Weights VGPR-resident, fp32 h state in registers. Mailbox sync
// (v12: private reader rows, scatter fan-out, no RMW).
// v14 vs v12 — ONE change: consumer stream loads drop `sc0`.
//   H5 (from v13 probe): sync hop measured ~0.6us => the ~10.2us step is the
//   LB BODY. Logical stream reads are 28MB/step; 28MB/10.4us = 2.7 TB/s =
//   MALL-BW-bound. SC bits on loads encode coherence SCOPE on gfx9xx;
//   device-scope loads must bypass the non-coherent per-XCD L2 => every
//   stream read was a MALL transaction, no L2 dedup of the 16 same-XCD
//   blocks reading the same 128KB slot. Plain cached loads restore L1+L2
//   fill; per-XCD MALL traffic drops ~10x.
//   Safety (capacity): a consumer can only hold a ring line cached >=1 lap
//   ago (256/512 steps). Per-XCD fresh inflow ~450KB/step through 4MB L2 =>
//   ~9-step LRU retention; survival over 256+ steps ~ e^-30. L1 laps every
//   fraction of a step. Producer agent write-through (st8c) unchanged =>
//   MALL always fresh; L2/L1 misses always fill fresh.
// Ledger: DVFS (v8 null), poll congestion (v9 null), load depth (v10 null),
// chain order/fusion (v11 null), reader-line contention (v12 ~null),
// sync-hop cost (v13 probe: 0.6us => body-bound).

#define Tn 1024
#define Hn 1024
#define INn 512

typedef short s8v __attribute__((ext_vector_type(8)));
typedef float f4v __attribute__((ext_vector_type(4)));
typedef unsigned short us4v __attribute__((ext_vector_type(4)));
typedef unsigned long long ull;

// ws layout (bytes)
#define WS_XB  0u           // x bf16 [64][1024][512]            = 67,108,864
#define WS_H0R 67108864u    // ring [512][ktile64][b64][16] bf16 = 67,108,864
#define WS_H1R 134217728u   // ring [256][ktile64][b64][16] bf16 = 33,554,432
#define WS_MB  167772160u   // mailbox [8][64][64] int           =    131,072

__device__ __forceinline__ unsigned short f2bf(float f) {
  unsigned int u = __float_as_uint(f);
  u += 0x7fffu + ((u >> 16) & 1u);
  return (unsigned short)(u >> 16);
}

__device__ __forceinline__ s8v pack8(const float* p) {
  float4 a = *(const float4*)p;
  float4 b = *(const float4*)(p + 4);
  s8v r;
  r[0] = (short)f2bf(a.x); r[1] = (short)f2bf(a.y);
  r[2] = (short)f2bf(a.z); r[3] = (short)f2bf(a.w);
  r[4] = (short)f2bf(b.x); r[5] = (short)f2bf(b.y);
  r[6] = (short)f2bf(b.z); r[7] = (short)f2bf(b.w);
  return r;
}

// producer store: relaxed agent-scope 8B atomic = write-through to MALL (v3+)
__device__ __forceinline__ void st8c(unsigned short* p, us4v v) {
  union { us4v v; ull u; } c; c.v = v;
  __hip_atomic_store((ull*)p, c.u, __ATOMIC_RELAXED, __HIP_MEMORY_SCOPE_AGENT);
}

// nt store via asm: ordered against other asm/memory ops (drain-count safety)
__device__ __forceinline__ void stnt16(float* p, f4v v) {
  asm volatile("global_store_dwordx4 %0, %1, off nt" :: "v"(p), "v"(v) : "memory");
}

// v14: consumer loads PLAIN CACHED (no sc0) — L1+L2 fill. Deep rings make
// stale-line retention impossible by capacity (see header). asm form kept
// so the counted-vmcnt pipeline in stream_gemm_deep stays exact.
__device__ __forceinline__ void issue4c(s8v* f, const unsigned short* src,
                                        int kt, int w, int rl, int kg) {
#pragma unroll
  for (int m = 0; m < 4; ++m) {
    const unsigned short* p = src + (size_t)(w * 16 + kt * 2 + (kg >> 1)) * 1024
                              + (m * 16 + rl) * 16 + (kg & 1) * 8;
    asm volatile("global_load_dwordx4 %0, %1, off"
                 : "=v"(f[m]) : "v"(p) : "memory");
  }
}

template<int N> __device__ __forceinline__ void vmwait() {
  asm volatile("s_waitcnt vmcnt(%0)" :: "i"(N) : "memory");
  __builtin_amdgcn_sched_barrier(0);
}

__device__ __forceinline__ void mfma3(f4v (*acc)[4], s8v w0, s8v w1, s8v w2,
                                      const s8v f[4], const int gl) {
#pragma unroll
  for (int m = 0; m < 4; ++m) {
    acc[m][0]  = __builtin_amdgcn_mfma_f32_16x16x32_bf16(w0, f[m], acc[m][0], 0, 0, 0);
    acc[m][1]  = __builtin_amdgcn_mfma_f32_16x16x32_bf16(w1, f[m], acc[m][1], 0, 0, 0);
    acc[m][gl] = __builtin_amdgcn_mfma_f32_16x16x32_bf16(w2, f[m], acc[m][gl], 0, 0, 0);
  }
}

// v10 deep-pipelined stream GEMM: pre-issue 24 loads (depth-6 fragment ring),
// consume with descending counted vmcnt, re-issue after consume (WAR-safe).
// Precondition: vmcnt == 0 on entry; self-drains on exit.
template<int GL>
__device__ __forceinline__ void stream_gemm_deep(f4v (*acc)[4], const s8v (*wgt)[8],
    const unsigned short* src, int w, int rl, int kg) {
  s8v f[6][4];
#pragma unroll
  for (int kt = 0; kt < 6; ++kt) issue4c(f[kt], src, kt, w, rl, kg);
  vmwait<20>(); mfma3(acc, wgt[0][0], wgt[1][0], wgt[2][0], f[0], GL);
  issue4c(f[0], src, 6, w, rl, kg);
  vmwait<20>(); mfma3(acc, wgt[0][1], wgt[1][1], wgt[2][1], f[1], GL);
  issue4c(f[1], src, 7, w, rl, kg);
  vmwait<20>(); mfma3(acc, wgt[0][2], wgt[1][2], wgt[2][2], f[2], GL);
  vmwait<16>(); mfma3(acc, wgt[0][3], wgt[1][3], wgt[2][3], f[3], GL);
  vmwait<12>(); mfma3(acc, wgt[0][4], wgt[1][4], wgt[2][4], f[4], GL);
  vmwait<8>();  mfma3(acc, wgt[0][5], wgt[1][5], wgt[2][5], f[5], GL);
  vmwait<4>();  mfma3(acc, wgt[0][6], wgt[1][6], wgt[2][6], f[0], GL);
  vmwait<0>();  mfma3(acc, wgt[0][7], wgt[1][7], wgt[2][7], f[1], GL);
}

__global__ void cvt_bf16_kernel(const float* __restrict__ src,
                                unsigned short* __restrict__ dst, int n4) {
  int i = blockIdx.x * blockDim.x + threadIdx.x;
  int st = gridDim.x * blockDim.x;
  for (; i < n4; i += st) {
    const float4 v = *(const float4*)(src + 4 * (size_t)i);
    us4v o;
    o[0] = f2bf(v.x); o[1] = f2bf(v.y); o[2] = f2bf(v.z); o[3] = f2bf(v.w);
    *(us4v*)(dst + 4 * (size_t)i) = o;
  }
}

__global__ void init_all(const float* __restrict__ h0in, char* __restrict__ ws) {
  int i = blockIdx.x * blockDim.x + threadIdx.x;   // grid 528*256 = 135168
  unsigned short* h0r = (unsigned short*)(ws + WS_H0R);
  unsigned short* h1r = (unsigned short*)(ws + WS_H1R);
  int* MB = (int*)(ws + WS_MB);
  if (i < 65536) {
    int b = i >> 10, h = i & 1023;
    int off = (h >> 4) * 1024 + b * 16 + (h & 15);
    h0r[511 * 65536 + off] = f2bf(h0in[i]);          // slot for step -1
    h1r[255 * 65536 + off] = f2bf(h0in[65536 + i]);  // slot for step -1
  }
  if (i < 32768) MB[i] = 0;                          // all mailbox groups: 0
}

// consumer wait: 64-lane gather over this block's PRIVATE mailbox rows
// (sole reader per line). row index = grp*64 + consumer; lane = producer.
__device__ __forceinline__ void mb_wait(const int* MB, int r1, int t1,
                                        int r2, int t2, int lane) {
  const int* p1 = MB + (r1 * 64 + lane);
  const int* p2 = MB + (r2 * 64 + lane);
  int tries = 0;
  for (;;) {
    int v1 = __hip_atomic_load(p1, __ATOMIC_RELAXED, __HIP_MEMORY_SCOPE_AGENT);
    int v2 = __hip_atomic_load(p2, __ATOMIC_RELAXED, __HIP_MEMORY_SCOPE_AGENT);
    if (__all(v1 >= t1 && v2 >= t2)) return;
    __builtin_amdgcn_s_sleep(1);
    if (++tries > (1 << 22)) return;   // fail visibly, never hang
  }
}

__global__ __launch_bounds__(256, 1) void gru_persist(
    const float* __restrict__ h0in,
    const float* __restrict__ wih0, const float* __restrict__ whh0,
    const float* __restrict__ bih0, const float* __restrict__ bhh0,
    const float* __restrict__ wih1, const float* __restrict__ whh1,
    const float* __restrict__ bih1, const float* __restrict__ bhh1,
    float* __restrict__ out, char* __restrict__ ws)
{
  const unsigned short* xb = (const unsigned short*)(ws + WS_XB);
  unsigned short* h0r = (unsigned short*)(ws + WS_H0R);
  unsigned short* h1r = (unsigned short*)(ws + WS_H1R);
  int* MB = (int*)(ws + WS_MB);

  const int blk = blockIdx.x;
  const int tid = threadIdx.x;

  if (blk >= 128) {
    // busy-clock pad (insurance): NO LDS, NO barriers — each wave polls its
    // block's grp2 mailbox row every ~33k cy; exits when all LB steps done.
    const int c = blk & 63;
    float a0 = 1.0f + (float)tid * 1e-6f, a1 = a0 + 0.25f;
    float a2 = a0 + 0.5f, a3 = a0 + 0.75f;
    const float mm = 0.99999988f, cc = 1e-7f;
    int run = 1;
    for (int it = 0; it < (1 << 17) && run; ++it) {
#pragma unroll
      for (int u = 0; u < 256; ++u) {
        a0 = __builtin_fmaf(a0, mm, cc); a1 = __builtin_fmaf(a1, mm, cc);
        a2 = __builtin_fmaf(a2, mm, cc); a3 = __builtin_fmaf(a3, mm, cc);
      }
      if ((it & 15) == 0) {
        int v = __hip_atomic_load(MB + (((2 * 64) + c) * 64 + (tid & 63)),
                                  __ATOMIC_RELAXED, __HIP_MEMORY_SCOPE_AGENT);
        if (__all(v >= Tn)) run = 0;
      }
    }
    asm volatile("" :: "v"(a0), "v"(a1), "v"(a2), "v"(a3));  // keep chains live
    return;
  }

  const bool isA = blk < 64;
  const int jt = blk & 63, jj = jt * 16;
  const int w = tid >> 6;                    // wave = K-slice = owner m-group
  const int lane = tid & 63;
  const int rl = lane & 15, kg = lane >> 4;

  __shared__ float cmb[4][4][64][20];        // stride 80B: conflict-free (r6)

  const int b = w * 16 + rl;                 // owner batch row (epilogue)
  const int j0 = jj + kg * 4;                // owner j base (epilogue)

  // ---- VGPR-resident weights ----
  const float* Wi = isA ? wih0 : wih1;
  const float* Wh = isA ? whh0 : whh1;
  const float* bi = isA ? bih0 : bih1;
  const float* bh = isA ? bhh0 : bhh1;
  const int Kx = isA ? INn : Hn;             // input-side K
  s8v wx[3][8], wh_[3][8];
  const int nkx = Kx / 128;                  // 4 (LA) or 8 (LB) k-tiles of 32
#pragma unroll
  for (int g = 0; g < 3; ++g) {
    for (int kt = 0; kt < nkx; ++kt)
      wx[g][kt] = pack8(Wi + (size_t)(g * 1024 + jj + rl) * Kx + w * (Kx / 4) + kt * 32 + kg * 8);
#pragma unroll
    for (int kt = 0; kt < 8; ++kt)
      wh_[g][kt] = pack8(Wh + (size_t)(g * 1024 + jj + rl) * Hn + w * 256 + kt * 32 + kg * 8);
  }
  const f4v bir = *(const f4v*)(bi + j0),        bhr = *(const f4v*)(bh + j0);
  const f4v biz = *(const f4v*)(bi + 1024 + j0), bhz = *(const f4v*)(bh + 1024 + j0);
  const f4v bin = *(const f4v*)(bi + 2048 + j0), bhn = *(const f4v*)(bh + 2048 + j0);

  // ---- register-resident fp32 hidden state (this thread's (b, j0..j0+3)) ----
  f4v hv = *(const f4v*)(h0in + (isA ? 0u : 65536u) + (size_t)b * Hn + j0);

  for (int s = 0; s < Tn; ++s) {
    // 1. LA: prefetch x fragments (plain cached loads, v4-proven) before spin
    s8v bx[4][4];
    if (isA) {
#pragma unroll
      for (int m = 0; m < 4; ++m)
#pragma unroll
        for (int kt = 0; kt < 4; ++kt)
          bx[m][kt] = *(const s8v*)(xb + ((size_t)(m * 16 + rl) * Tn + s) * INn + w * 128 + kt * 32 + kg * 8);
    }
    // 2. mailbox wait (wave0 only; private rows, sole reader per line)
    if (w == 0) {
      if (isA) mb_wait(MB, 0 * 64 + jt, s,     3 * 64 + jt, s - 255, lane);
      else     mb_wait(MB, 1 * 64 + jt, s + 1, 2 * 64 + jt, s,       lane);
    }
    __syncthreads();
    vmwait<0>();                             // clean baseline for counted pipe

    f4v acc[4][4];
#pragma unroll
    for (int m = 0; m < 4; ++m)
#pragma unroll
      for (int g = 0; g < 4; ++g) acc[m][g] = (f4v){0.f, 0.f, 0.f, 0.f};

    // deep-ring slots (no address reuse within 256+ steps => cache-safe)
    const unsigned short* hsrc = isA ? (h0r + (size_t)((s - 1) & 511) * 65536)
                                     : (h1r + (size_t)((s - 1) & 255) * 65536);
    const unsigned short* asrc = h0r + (size_t)(s & 511) * 65536;  // LB input h0[s]

    if (isA) {
      // 3a. x-GEMM from registers
#pragma unroll
      for (int kt = 0; kt < 4; ++kt) {
        s8v f4[4] = { bx[0][kt], bx[1][kt], bx[2][kt], bx[3][kt] };
        mfma3(acc, wx[0][kt], wx[1][kt], wx[2][kt], f4, 2);
      }
      // 3b. hidden stream, deep-pipelined
      stream_gemm_deep<3>(acc, wh_, hsrc, w, rl, kg);
    } else {
      // 3. a-stream then h-stream, each deep-pipelined (self-draining)
      stream_gemm_deep<2>(acc, wx, asrc, w, rl, kg);
      stream_gemm_deep<3>(acc, wh_, hsrc, w, rl, kg);
    }

    // 4. cross-wave K-combine (LDS)
#pragma unroll
    for (int d = 0; d < 4; ++d) if (d != w)
#pragma unroll
      for (int g = 0; g < 4; ++g) *(f4v*)&cmb[d][w][lane][g * 4] = acc[d][g];
    __syncthreads();
    f4v hsum[4];
#pragma unroll
    for (int g = 0; g < 4; ++g) {
      hsum[g] = acc[w][g];
#pragma unroll
      for (int src = 0; src < 4; ++src) if (src != w) hsum[g] += *(f4v*)&cmb[w][src][lane][g * 4];
    }

    // 5. epilogue: gates + zoneout, state stays in hv registers
    us4v hb4;
#pragma unroll
    for (int rr = 0; rr < 4; ++rr) {
      float hp = hv[rr];
      float rg = 1.f / (1.f + __expf(-(hsum[0][rr] + bir[rr] + bhr[rr])));
      float zg = 1.f / (1.f + __expf(-(hsum[1][rr] + biz[rr] + bhz[rr])));
      float narg = hsum[2][rr] + bin[rr] + rg * (hsum[3][rr] + bhn[rr]);
      float e2 = __expf(2.f * narg);
      float ng = 1.f - 2.f / (e2 + 1.f);
      float nv = (1.f - zg) * ng + zg * hp;
      hv[rr] = 0.1f * hp + 0.9f * nv;
    }
    hb4[0] = f2bf(hv[0]); hb4[1] = f2bf(hv[1]); hb4[2] = f2bf(hv[2]); hb4[3] = f2bf(hv[3]);

    // 6. broadcast bf16 h (write-through 8B atomics, issued FIRST), then out
    //    nt-stores; counted drain: wait only until st8c is acked.
    if (isA) {
      st8c(h0r + (size_t)(s & 511) * 65536 + jt * 1024 + b * 16 + kg * 4, hb4);
      if (s == Tn - 1)
        stnt16(out + 67108864u + (size_t)b * Hn + j0, hv);
      vmwait<0>();                           // st8c (+final store) acked
    } else {
      st8c(h1r + (size_t)(s & 255) * 65536 + jt * 1024 + b * 16 + kg * 4, hb4);
      stnt16(out + ((size_t)b * Tn + s) * Hn + j0, hv);
      if (s == Tn - 1) {
        stnt16(out + 67108864u + 65536u + (size_t)b * Hn + j0, hv);
        vmwait<0>();
      } else {
        vmwait<1>();                         // st8c acked; out-store off-chain
      }
    }
    __syncthreads();
    // 7. flag fan-out: wave0's 64 lanes scatter (s+1) to the 64 consumer
    //    rows of each served group (plain relaxed stores, no RMW).
    if (tid < 64) {
      const int g1 = isA ? 0 : 2, g2 = isA ? 1 : 3;
      __hip_atomic_store(MB + ((g1 * 64 + tid) * 64 + jt), s + 1,
                         __ATOMIC_RELAXED, __HIP_MEMORY_SCOPE_AGENT);
      __hip_atomic_store(MB + ((g2 * 64 + tid) * 64 + jt), s + 1,
                         __ATOMIC_RELAXED, __HIP_MEMORY_SCOPE_AGENT);
    }
  }
}

extern "C" void kernel_launch(void* const* d_in, const int* in_sizes, int n_in,
                              void* d_out, int out_size, void* d_ws, size_t ws_size,
                              hipStream_t stream) {
  (void)in_sizes; (void)n_in; (void)out_size; (void)ws_size;
  const float* x    = (const float*)d_in[0];
  const float* h0in = (const float*)d_in[1];
  const float* wih0 = (const float*)d_in[2];
  const float* whh0 = (const float*)d_in[3];
  const float* bih0 = (const float*)d_in[4];
  const float* bhh0 = (const float*)d_in[5];
  const float* wih1 = (const float*)d_in[6];
  const float* whh1 = (const float*)d_in[7];
  const float* bih1 = (const float*)d_in[8];
  const float* bhh1 = (const float*)d_in[9];
  float* out = (float*)d_out;
  char* ws = (char*)d_ws;

  cvt_bf16_kernel<<<2048, 256, 0, stream>>>(x, (unsigned short*)(ws + WS_XB), 33554432 / 4);
  init_all<<<528, 256, 0, stream>>>(h0in, ws);
  gru_persist<<<dim3(256), dim3(256), 0, stream>>>(
      h0in, wih0, whh0, bih0, bhh0, wih1, whh1, bih1, bhh1, out, ws);
}

// Round 9
// 10156.041 us; speedup vs baseline: 1.1095x; 1.0425x over previous
//
#include <hip/hip_runtime.h>

// ZoneoutGRU persistent kernel v16: B=64, T=1024, IN=512, H=1024, L=2, zo=0.1.
// 128 active blocks (64 LA = layer0, 64 LB = layer1), 256 thr (4 waves = K
// slices). Mailbox sync (v12), plain cached stream loads (v14).
// v16 vs v14 — ONE change: __attribute__((amdgpu_waves_per_eu(1,1))).
//   H6: LB live-register demand ~395 VGPRs (wx 96 + wh 96 + acc 64 + f-ring
//   96 + biases/misc ~45) but VGPR_Count was 216 (180 in v7): the allocator
//   targeted 2 waves/EU and SPILLED ~180 VGPRs. The "VGPR-resident weights"
//   have been scratch-resident in the LB loop since v4 — tens of KB per wave
//   per step of latency-chained spill reloads, untouched by every protocol/
//   stream experiment (explains the v8-v14 null ledger). We run 1 block/CU =
//   1 wave/SIMD anyway, so forcing 1 wave/EU costs nothing and unlocks the
//   full ~512-VGPR file (no-spill headroom ~450 per uarch notes).
//   Verification channel: VGPR_Count must jump to ~380-450, scratch to 0.
// Ledger: DVFS(v8) poll(v9) depth(v10) order(v11) flaglines(v12) cache(v14)
// null; hop=0.6us (v13); v15 probe crashed (same-dest-VGPR load hazard).

#define Tn 1024
#define Hn 1024
#define INn 512

typedef short s8v __attribute__((ext_vector_type(8)));
typedef float f4v __attribute__((ext_vector_type(4)));
typedef unsigned short us4v __attribute__((ext_vector_type(4)));
typedef unsigned long long ull;

// ws layout (bytes)
#define WS_XB  0u           // x bf16 [64][1024][512]            = 67,108,864
#define WS_H0R 67108864u    // ring [512][ktile64][b64][16] bf16 = 67,108,864
#define WS_H1R 134217728u   // ring [256][ktile64][b64][16] bf16 = 33,554,432
#define WS_MB  167772160u   // mailbox [8][64][64] int           =    131,072

__device__ __forceinline__ unsigned short f2bf(float f) {
  unsigned int u = __float_as_uint(f);
  u += 0x7fffu + ((u >> 16) & 1u);
  return (unsigned short)(u >> 16);
}

__device__ __forceinline__ s8v pack8(const float* p) {
  float4 a = *(const float4*)p;
  float4 b = *(const float4*)(p + 4);
  s8v r;
  r[0] = (short)f2bf(a.x); r[1] = (short)f2bf(a.y);
  r[2] = (short)f2bf(a.z); r[3] = (short)f2bf(a.w);
  r[4] = (short)f2bf(b.x); r[5] = (short)f2bf(b.y);
  r[6] = (short)f2bf(b.z); r[7] = (short)f2bf(b.w);
  return r;
}

// producer store: relaxed agent-scope 8B atomic = write-through to MALL (v3+)
__device__ __forceinline__ void st8c(unsigned short* p, us4v v) {
  union { us4v v; ull u; } c; c.v = v;
  __hip_atomic_store((ull*)p, c.u, __ATOMIC_RELAXED, __HIP_MEMORY_SCOPE_AGENT);
}

// nt store via asm: ordered against other asm/memory ops (drain-count safety)
__device__ __forceinline__ void stnt16(float* p, f4v v) {
  asm volatile("global_store_dwordx4 %0, %1, off nt" :: "v"(p), "v"(v) : "memory");
}

// consumer loads: plain cached (v14)
__device__ __forceinline__ void issue4c(s8v* f, const unsigned short* src,
                                        int kt, int w, int rl, int kg) {
#pragma unroll
  for (int m = 0; m < 4; ++m) {
    const unsigned short* p = src + (size_t)(w * 16 + kt * 2 + (kg >> 1)) * 1024
                              + (m * 16 + rl) * 16 + (kg & 1) * 8;
    asm volatile("global_load_dwordx4 %0, %1, off"
                 : "=v"(f[m]) : "v"(p) : "memory");
  }
}

template<int N> __device__ __forceinline__ void vmwait() {
  asm volatile("s_waitcnt vmcnt(%0)" :: "i"(N) : "memory");
  __builtin_amdgcn_sched_barrier(0);
}

__device__ __forceinline__ void mfma3(f4v (*acc)[4], s8v w0, s8v w1, s8v w2,
                                      const s8v f[4], const int gl) {
#pragma unroll
  for (int m = 0; m < 4; ++m) {
    acc[m][0]  = __builtin_amdgcn_mfma_f32_16x16x32_bf16(w0, f[m], acc[m][0], 0, 0, 0);
    acc[m][1]  = __builtin_amdgcn_mfma_f32_16x16x32_bf16(w1, f[m], acc[m][1], 0, 0, 0);
    acc[m][gl] = __builtin_amdgcn_mfma_f32_16x16x32_bf16(w2, f[m], acc[m][gl], 0, 0, 0);
  }
}

// v10 deep-pipelined stream GEMM: pre-issue 24 loads (depth-6 fragment ring),
// consume with descending counted vmcnt, re-issue after consume (WAR-safe).
// Precondition: vmcnt == 0 on entry; self-drains on exit.
template<int GL>
__device__ __forceinline__ void stream_gemm_deep(f4v (*acc)[4], const s8v (*wgt)[8],
    const unsigned short* src, int w, int rl, int kg) {
  s8v f[6][4];
#pragma unroll
  for (int kt = 0; kt < 6; ++kt) issue4c(f[kt], src, kt, w, rl, kg);
  vmwait<20>(); mfma3(acc, wgt[0][0], wgt[1][0], wgt[2][0], f[0], GL);
  issue4c(f[0], src, 6, w, rl, kg);
  vmwait<20>(); mfma3(acc, wgt[0][1], wgt[1][1], wgt[2][1], f[1], GL);
  issue4c(f[1], src, 7, w, rl, kg);
  vmwait<20>(); mfma3(acc, wgt[0][2], wgt[1][2], wgt[2][2], f[2], GL);
  vmwait<16>(); mfma3(acc, wgt[0][3], wgt[1][3], wgt[2][3], f[3], GL);
  vmwait<12>(); mfma3(acc, wgt[0][4], wgt[1][4], wgt[2][4], f[4], GL);
  vmwait<8>();  mfma3(acc, wgt[0][5], wgt[1][5], wgt[2][5], f[5], GL);
  vmwait<4>();  mfma3(acc, wgt[0][6], wgt[1][6], wgt[2][6], f[0], GL);
  vmwait<0>();  mfma3(acc, wgt[0][7], wgt[1][7], wgt[2][7], f[1], GL);
}

__global__ void cvt_bf16_kernel(const float* __restrict__ src,
                                unsigned short* __restrict__ dst, int n4) {
  int i = blockIdx.x * blockDim.x + threadIdx.x;
  int st = gridDim.x * blockDim.x;
  for (; i < n4; i += st) {
    const float4 v = *(const float4*)(src + 4 * (size_t)i);
    us4v o;
    o[0] = f2bf(v.x); o[1] = f2bf(v.y); o[2] = f2bf(v.z); o[3] = f2bf(v.w);
    *(us4v*)(dst + 4 * (size_t)i) = o;
  }
}

__global__ void init_all(const float* __restrict__ h0in, char* __restrict__ ws) {
  int i = blockIdx.x * blockDim.x + threadIdx.x;   // grid 528*256 = 135168
  unsigned short* h0r = (unsigned short*)(ws + WS_H0R);
  unsigned short* h1r = (unsigned short*)(ws + WS_H1R);
  int* MB = (int*)(ws + WS_MB);
  if (i < 65536) {
    int b = i >> 10, h = i & 1023;
    int off = (h >> 4) * 1024 + b * 16 + (h & 15);
    h0r[511 * 65536 + off] = f2bf(h0in[i]);          // slot for step -1
    h1r[255 * 65536 + off] = f2bf(h0in[65536 + i]);  // slot for step -1
  }
  if (i < 32768) MB[i] = 0;                          // all mailbox groups: 0
}

// consumer wait: 64-lane gather over this block's PRIVATE mailbox rows
// (sole reader per line). row index = grp*64 + consumer; lane = producer.
__device__ __forceinline__ void mb_wait(const int* MB, int r1, int t1,
                                        int r2, int t2, int lane) {
  const int* p1 = MB + (r1 * 64 + lane);
  const int* p2 = MB + (r2 * 64 + lane);
  int tries = 0;
  for (;;) {
    int v1 = __hip_atomic_load(p1, __ATOMIC_RELAXED, __HIP_MEMORY_SCOPE_AGENT);
    int v2 = __hip_atomic_load(p2, __ATOMIC_RELAXED, __HIP_MEMORY_SCOPE_AGENT);
    if (__all(v1 >= t1 && v2 >= t2)) return;
    __builtin_amdgcn_s_sleep(1);
    if (++tries > (1 << 22)) return;   // fail visibly, never hang
  }
}

__global__ __launch_bounds__(256)
__attribute__((amdgpu_waves_per_eu(1, 1)))        // v16: unlock full VGPR file
void gru_persist(
    const float* __restrict__ h0in,
    const float* __restrict__ wih0, const float* __restrict__ whh0,
    const float* __restrict__ bih0, const float* __restrict__ bhh0,
    const float* __restrict__ wih1, const float* __restrict__ whh1,
    const float* __restrict__ bih1, const float* __restrict__ bhh1,
    float* __restrict__ out, char* __restrict__ ws)
{
  const unsigned short* xb = (const unsigned short*)(ws + WS_XB);
  unsigned short* h0r = (unsigned short*)(ws + WS_H0R);
  unsigned short* h1r = (unsigned short*)(ws + WS_H1R);
  int* MB = (int*)(ws + WS_MB);

  const int blk = blockIdx.x;
  const int tid = threadIdx.x;

  if (blk >= 128) {
    // busy-clock pad (insurance): NO LDS, NO barriers — each wave polls its
    // block's grp2 mailbox row every ~33k cy; exits when all LB steps done.
    const int c = blk & 63;
    float a0 = 1.0f + (float)tid * 1e-6f, a1 = a0 + 0.25f;
    float a2 = a0 + 0.5f, a3 = a0 + 0.75f;
    const float mm = 0.99999988f, cc = 1e-7f;
    int run = 1;
    for (int it = 0; it < (1 << 17) && run; ++it) {
#pragma unroll
      for (int u = 0; u < 256; ++u) {
        a0 = __builtin_fmaf(a0, mm, cc); a1 = __builtin_fmaf(a1, mm, cc);
        a2 = __builtin_fmaf(a2, mm, cc); a3 = __builtin_fmaf(a3, mm, cc);
      }
      if ((it & 15) == 0) {
        int v = __hip_atomic_load(MB + (((2 * 64) + c) * 64 + (tid & 63)),
                                  __ATOMIC_RELAXED, __HIP_MEMORY_SCOPE_AGENT);
        if (__all(v >= Tn)) run = 0;
      }
    }
    asm volatile("" :: "v"(a0), "v"(a1), "v"(a2), "v"(a3));  // keep chains live
    return;
  }

  const bool isA = blk < 64;
  const int jt = blk & 63, jj = jt * 16;
  const int w = tid >> 6;                    // wave = K-slice = owner m-group
  const int lane = tid & 63;
  const int rl = lane & 15, kg = lane >> 4;

  __shared__ float cmb[4][4][64][20];        // stride 80B: conflict-free (r6)

  const int b = w * 16 + rl;                 // owner batch row (epilogue)
  const int j0 = jj + kg * 4;                // owner j base (epilogue)

  // ---- VGPR-resident weights (now actually resident: 1 wave/EU alloc) ----
  const float* Wi = isA ? wih0 : wih1;
  const float* Wh = isA ? whh0 : whh1;
  const float* bi = isA ? bih0 : bih1;
  const float* bh = isA ? bhh0 : bhh1;
  const int Kx = isA ? INn : Hn;             // input-side K
  s8v wx[3][8], wh_[3][8];
  const int nkx = Kx / 128;                  // 4 (LA) or 8 (LB) k-tiles of 32
#pragma unroll
  for (int g = 0; g < 3; ++g) {
    for (int kt = 0; kt < nkx; ++kt)
      wx[g][kt] = pack8(Wi + (size_t)(g * 1024 + jj + rl) * Kx + w * (Kx / 4) + kt * 32 + kg * 8);
#pragma unroll
    for (int kt = 0; kt < 8; ++kt)
      wh_[g][kt] = pack8(Wh + (size_t)(g * 1024 + jj + rl) * Hn + w * 256 + kt * 32 + kg * 8);
  }
  const f4v bir = *(const f4v*)(bi + j0),        bhr = *(const f4v*)(bh + j0);
  const f4v biz = *(const f4v*)(bi + 1024 + j0), bhz = *(const f4v*)(bh + 1024 + j0);
  const f4v bin = *(const f4v*)(bi + 2048 + j0), bhn = *(const f4v*)(bh + 2048 + j0);

  // ---- register-resident fp32 hidden state (this thread's (b, j0..j0+3)) ----
  f4v hv = *(const f4v*)(h0in + (isA ? 0u : 65536u) + (size_t)b * Hn + j0);

  for (int s = 0; s < Tn; ++s) {
    // 1. LA: prefetch x fragments (plain cached loads, v4-proven) before spin
    s8v bx[4][4];
    if (isA) {
#pragma unroll
      for (int m = 0; m < 4; ++m)
#pragma unroll
        for (int kt = 0; kt < 4; ++kt)
          bx[m][kt] = *(const s8v*)(xb + ((size_t)(m * 16 + rl) * Tn + s) * INn + w * 128 + kt * 32 + kg * 8);
    }
    // 2. mailbox wait (wave0 only; private rows, sole reader per line)
    if (w == 0) {
      if (isA) mb_wait(MB, 0 * 64 + jt, s,     3 * 64 + jt, s - 255, lane);
      else     mb_wait(MB, 1 * 64 + jt, s + 1, 2 * 64 + jt, s,       lane);
    }
    __syncthreads();
    vmwait<0>();                             // clean baseline for counted pipe

    f4v acc[4][4];
#pragma unroll
    for (int m = 0; m < 4; ++m)
#pragma unroll
      for (int g = 0; g < 4; ++g) acc[m][g] = (f4v){0.f, 0.f, 0.f, 0.f};

    // deep-ring slots (no address reuse within 256+ steps => cache-safe)
    const unsigned short* hsrc = isA ? (h0r + (size_t)((s - 1) & 511) * 65536)
                                     : (h1r + (size_t)((s - 1) & 255) * 65536);
    const unsigned short* asrc = h0r + (size_t)(s & 511) * 65536;  // LB input h0[s]

    if (isA) {
      // 3a. x-GEMM from registers
#pragma unroll
      for (int kt = 0; kt < 4; ++kt) {
        s8v f4[4] = { bx[0][kt], bx[1][kt], bx[2][kt], bx[3][kt] };
        mfma3(acc, wx[0][kt], wx[1][kt], wx[2][kt], f4, 2);
      }
      // 3b. hidden stream, deep-pipelined
      stream_gemm_deep<3>(acc, wh_, hsrc, w, rl, kg);
    } else {
      // 3. a-stream then h-stream, each deep-pipelined (self-draining)
      stream_gemm_deep<2>(acc, wx, asrc, w, rl, kg);
      stream_gemm_deep<3>(acc, wh_, hsrc, w, rl, kg);
    }

    // 4. cross-wave K-combine (LDS)
#pragma unroll
    for (int d = 0; d < 4; ++d) if (d != w)
#pragma unroll
      for (int g = 0; g < 4; ++g) *(f4v*)&cmb[d][w][lane][g * 4] = acc[d][g];
    __syncthreads();
    f4v hsum[4];
#pragma unroll
    for (int g = 0; g < 4; ++g) {
      hsum[g] = acc[w][g];
#pragma unroll
      for (int src = 0; src < 4; ++src) if (src != w) hsum[g] += *(f4v*)&cmb[w][src][lane][g * 4];
    }

    // 5. epilogue: gates + zoneout, state stays in hv registers
    us4v hb4;
#pragma unroll
    for (int rr = 0; rr < 4; ++rr) {
      float hp = hv[rr];
      float rg = 1.f / (1.f + __expf(-(hsum[0][rr] + bir[rr] + bhr[rr])));
      float zg = 1.f / (1.f + __expf(-(hsum[1][rr] + biz[rr] + bhz[rr])));
      float narg = hsum[2][rr] + bin[rr] + rg * (hsum[3][rr] + bhn[rr]);
      float e2 = __expf(2.f * narg);
      float ng = 1.f - 2.f / (e2 + 1.f);
      float nv = (1.f - zg) * ng + zg * hp;
      hv[rr] = 0.1f * hp + 0.9f * nv;
    }
    hb4[0] = f2bf(hv[0]); hb4[1] = f2bf(hv[1]); hb4[2] = f2bf(hv[2]); hb4[3] = f2bf(hv[3]);

    // 6. broadcast bf16 h (write-through 8B atomics, issued FIRST), then out
    //    nt-stores; counted drain: wait only until st8c is acked.
    if (isA) {
      st8c(h0r + (size_t)(s & 511) * 65536 + jt * 1024 + b * 16 + kg * 4, hb4);
      if (s == Tn - 1)
        stnt16(out + 67108864u + (size_t)b * Hn + j0, hv);
      vmwait<0>();                           // st8c (+final store) acked
    } else {
      st8c(h1r + (size_t)(s & 255) * 65536 + jt * 1024 + b * 16 + kg * 4, hb4);
      stnt16(out + ((size_t)b * Tn + s) * Hn + j0, hv);
      if (s == Tn - 1) {
        stnt16(out + 67108864u + 65536u + (size_t)b * Hn + j0, hv);
        vmwait<0>();
      } else {
        vmwait<1>();                         // st8c acked; out-store off-chain
      }
    }
    __syncthreads();
    // 7. flag fan-out: wave0's 64 lanes scatter (s+1) to the 64 consumer
    //    rows of each served group (plain relaxed stores, no RMW).
    if (tid < 64) {
      const int g1 = isA ? 0 : 2, g2 = isA ? 1 : 3;
      __hip_atomic_store(MB + ((g1 * 64 + tid) * 64 + jt), s + 1,
                         __ATOMIC_RELAXED, __HIP_MEMORY_SCOPE_AGENT);
      __hip_atomic_store(MB + ((g2 * 64 + tid) * 64 + jt), s + 1,
                         __ATOMIC_RELAXED, __HIP_MEMORY_SCOPE_AGENT);
    }
  }
}

extern "C" void kernel_launch(void* const* d_in, const int* in_sizes, int n_in,
                              void* d_out, int out_size, void* d_ws, size_t ws_size,
                              hipStream_t stream) {
  (void)in_sizes; (void)n_in; (void)out_size; (void)ws_size;
  const float* x    = (const float*)d_in[0];
  const float* h0in = (const float*)d_in[1];
  const float* wih0 = (const float*)d_in[2];
  const float* whh0 = (const float*)d_in[3];
  const float* bih0 = (const float*)d_in[4];
  const float* bhh0 = (const float*)d_in[5];
  const float* wih1 = (const float*)d_in[6];
  const float* whh1 = (const float*)d_in[7];
  const float* bih1 = (const float*)d_in[8];
  const float* bhh1 = (const float*)d_in[9];
  float* out = (float*)d_out;
  char* ws = (char*)d_ws;

  cvt_bf16_kernel<<<2048, 256, 0, stream>>>(x, (unsigned short*)(ws + WS_XB), 33554432 / 4);
  init_all<<<528, 256, 0, stream>>>(h0in, ws);
  gru_persist<<<dim3(256), dim3(256), 0, stream>>>(
      h0in, wih0, whh0, bih0, bhh0, wih1, whh1, bih1, bhh1, out, ws);
}

// Round 11
// 7713.937 us; speedup vs baseline: 1.4607x; 1.3166x over previous
//
#include <hip/hip_runtime.h>

// ZoneoutGRU persistent kernel v18: B=64, T=1024, IN=512, H=1024, L=2, zo=0.1.
// 128 active blocks (64 LA, 64 LB), 256 thr (4 waves = K slices). Mailbox
// sync (v12), plain cached stream loads (v14), waves_per_eu(1,1) (v16).
// v18 = v16 + ONLY the rule-#20 fix (v17 minus the inline-asm MFMA that
// NaN'd — compiler hazard recognizer can't see into asm MFMA):
//  * BUG (since v4): weight-init loop `for(kt=0;kt<nkx;++kt)` with RUNTIME
//    nkx (isA?4:8) dynamically indexes wx[3][8] => array memory-homed =>
//    every weight read in the MFMA loop is a scratch/LDS load. Evidence:
//    v16 WRITE_SIZE 6.68GB -> 1.06GB (logical) when spills moved venue to
//    LDS (conflicts 0 -> 7.4e8, LDS 81920 -> 147456); dur unchanged =>
//    the reload CHAIN is the invariant binder of the v8-v16 null ledger.
//  * FIX: constant trip counts per layer branch (unroll 4 / unroll 8) =>
//    SROA promotes both weight arrays to the unified VGPR/AGPR file
//    (~406 regs needed < 512 available at 1 wave/EU). Builtin MFMA keeps
//    compiler-managed hazards.
// Verification channels: LDS_Block_Size ~81920, SQ_LDS_BANK_CONFLICT ~0,
// WRITE_SIZE ~1.06e6 KB, VGPR high. Ledger: DVFS(v8) poll(v9) depth(v10)
// order(v11) flaglines(v12) cache(v14) spill-venue(v16) null; hop=0.6us
// (v13); v15/v17 crashed (probe hazard / asm-MFMA hazard).

#define Tn 1024
#define Hn 1024
#define INn 512

typedef short s8v __attribute__((ext_vector_type(8)));
typedef float f4v __attribute__((ext_vector_type(4)));
typedef unsigned short us4v __attribute__((ext_vector_type(4)));
typedef unsigned long long ull;

// ws layout (bytes)
#define WS_XB  0u           // x bf16 [64][1024][512]            = 67,108,864
#define WS_H0R 67108864u    // ring [512][ktile64][b64][16] bf16 = 67,108,864
#define WS_H1R 134217728u   // ring [256][ktile64][b64][16] bf16 = 33,554,432
#define WS_MB  167772160u   // mailbox [8][64][64] int           =    131,072

__device__ __forceinline__ unsigned short f2bf(float f) {
  unsigned int u = __float_as_uint(f);
  u += 0x7fffu + ((u >> 16) & 1u);
  return (unsigned short)(u >> 16);
}

__device__ __forceinline__ s8v pack8(const float* p) {
  float4 a = *(const float4*)p;
  float4 b = *(const float4*)(p + 4);
  s8v r;
  r[0] = (short)f2bf(a.x); r[1] = (short)f2bf(a.y);
  r[2] = (short)f2bf(a.z); r[3] = (short)f2bf(a.w);
  r[4] = (short)f2bf(b.x); r[5] = (short)f2bf(b.y);
  r[6] = (short)f2bf(b.z); r[7] = (short)f2bf(b.w);
  return r;
}

// producer store: relaxed agent-scope 8B atomic = write-through to MALL (v3+)
__device__ __forceinline__ void st8c(unsigned short* p, us4v v) {
  union { us4v v; ull u; } c; c.v = v;
  __hip_atomic_store((ull*)p, c.u, __ATOMIC_RELAXED, __HIP_MEMORY_SCOPE_AGENT);
}

// nt store via asm: ordered against other asm/memory ops (drain-count safety)
__device__ __forceinline__ void stnt16(float* p, f4v v) {
  asm volatile("global_store_dwordx4 %0, %1, off nt" :: "v"(p), "v"(v) : "memory");
}

// consumer loads: plain cached (v14)
__device__ __forceinline__ void issue4c(s8v* f, const unsigned short* src,
                                        int kt, int w, int rl, int kg) {
#pragma unroll
  for (int m = 0; m < 4; ++m) {
    const unsigned short* p = src + (size_t)(w * 16 + kt * 2 + (kg >> 1)) * 1024
                              + (m * 16 + rl) * 16 + (kg & 1) * 8;
    asm volatile("global_load_dwordx4 %0, %1, off"
                 : "=v"(f[m]) : "v"(p) : "memory");
  }
}

template<int N> __device__ __forceinline__ void vmwait() {
  asm volatile("s_waitcnt vmcnt(%0)" :: "i"(N) : "memory");
  __builtin_amdgcn_sched_barrier(0);
}

__device__ __forceinline__ void mfma3(f4v (*acc)[4], s8v w0, s8v w1, s8v w2,
                                      const s8v f[4], const int gl) {
#pragma unroll
  for (int m = 0; m < 4; ++m) {
    acc[m][0]  = __builtin_amdgcn_mfma_f32_16x16x32_bf16(w0, f[m], acc[m][0], 0, 0, 0);
    acc[m][1]  = __builtin_amdgcn_mfma_f32_16x16x32_bf16(w1, f[m], acc[m][1], 0, 0, 0);
    acc[m][gl] = __builtin_amdgcn_mfma_f32_16x16x32_bf16(w2, f[m], acc[m][gl], 0, 0, 0);
  }
}

// v10 deep-pipelined stream GEMM: pre-issue 24 loads (depth-6 fragment ring),
// consume with descending counted vmcnt, re-issue after consume (WAR-safe).
// Precondition: vmcnt == 0 on entry; self-drains on exit.
template<int GL>
__device__ __forceinline__ void stream_gemm_deep(f4v (*acc)[4], const s8v (*wgt)[8],
    const unsigned short* src, int w, int rl, int kg) {
  s8v f[6][4];
#pragma unroll
  for (int kt = 0; kt < 6; ++kt) issue4c(f[kt], src, kt, w, rl, kg);
  vmwait<20>(); mfma3(acc, wgt[0][0], wgt[1][0], wgt[2][0], f[0], GL);
  issue4c(f[0], src, 6, w, rl, kg);
  vmwait<20>(); mfma3(acc, wgt[0][1], wgt[1][1], wgt[2][1], f[1], GL);
  issue4c(f[1], src, 7, w, rl, kg);
  vmwait<20>(); mfma3(acc, wgt[0][2], wgt[1][2], wgt[2][2], f[2], GL);
  vmwait<16>(); mfma3(acc, wgt[0][3], wgt[1][3], wgt[2][3], f[3], GL);
  vmwait<12>(); mfma3(acc, wgt[0][4], wgt[1][4], wgt[2][4], f[4], GL);
  vmwait<8>();  mfma3(acc, wgt[0][5], wgt[1][5], wgt[2][5], f[5], GL);
  vmwait<4>();  mfma3(acc, wgt[0][6], wgt[1][6], wgt[2][6], f[0], GL);
  vmwait<0>();  mfma3(acc, wgt[0][7], wgt[1][7], wgt[2][7], f[1], GL);
}

__global__ void cvt_bf16_kernel(const float* __restrict__ src,
                                unsigned short* __restrict__ dst, int n4) {
  int i = blockIdx.x * blockDim.x + threadIdx.x;
  int st = gridDim.x * blockDim.x;
  for (; i < n4; i += st) {
    const float4 v = *(const float4*)(src + 4 * (size_t)i);
    us4v o;
    o[0] = f2bf(v.x); o[1] = f2bf(v.y); o[2] = f2bf(v.z); o[3] = f2bf(v.w);
    *(us4v*)(dst + 4 * (size_t)i) = o;
  }
}

__global__ void init_all(const float* __restrict__ h0in, char* __restrict__ ws) {
  int i = blockIdx.x * blockDim.x + threadIdx.x;   // grid 528*256 = 135168
  unsigned short* h0r = (unsigned short*)(ws + WS_H0R);
  unsigned short* h1r = (unsigned short*)(ws + WS_H1R);
  int* MB = (int*)(ws + WS_MB);
  if (i < 65536) {
    int b = i >> 10, h = i & 1023;
    int off = (h >> 4) * 1024 + b * 16 + (h & 15);
    h0r[511 * 65536 + off] = f2bf(h0in[i]);          // slot for step -1
    h1r[255 * 65536 + off] = f2bf(h0in[65536 + i]);  // slot for step -1
  }
  if (i < 32768) MB[i] = 0;                          // all mailbox groups: 0
}

// consumer wait: 64-lane gather over this block's PRIVATE mailbox rows
// (sole reader per line). row index = grp*64 + consumer; lane = producer.
__device__ __forceinline__ void mb_wait(const int* MB, int r1, int t1,
                                        int r2, int t2, int lane) {
  const int* p1 = MB + (r1 * 64 + lane);
  const int* p2 = MB + (r2 * 64 + lane);
  int tries = 0;
  for (;;) {
    int v1 = __hip_atomic_load(p1, __ATOMIC_RELAXED, __HIP_MEMORY_SCOPE_AGENT);
    int v2 = __hip_atomic_load(p2, __ATOMIC_RELAXED, __HIP_MEMORY_SCOPE_AGENT);
    if (__all(v1 >= t1 && v2 >= t2)) return;
    __builtin_amdgcn_s_sleep(1);
    if (++tries > (1 << 22)) return;   // fail visibly, never hang
  }
}

__global__ __launch_bounds__(256)
__attribute__((amdgpu_waves_per_eu(1, 1)))   // 1 wave/EU: full unified RF
void gru_persist(
    const float* __restrict__ h0in,
    const float* __restrict__ wih0, const float* __restrict__ whh0,
    const float* __restrict__ bih0, const float* __restrict__ bhh0,
    const float* __restrict__ wih1, const float* __restrict__ whh1,
    const float* __restrict__ bih1, const float* __restrict__ bhh1,
    float* __restrict__ out, char* __restrict__ ws)
{
  const unsigned short* xb = (const unsigned short*)(ws + WS_XB);
  unsigned short* h0r = (unsigned short*)(ws + WS_H0R);
  unsigned short* h1r = (unsigned short*)(ws + WS_H1R);
  int* MB = (int*)(ws + WS_MB);

  const int blk = blockIdx.x;
  const int tid = threadIdx.x;

  if (blk >= 128) {
    // busy-clock pad (insurance): NO LDS, NO barriers — each wave polls its
    // block's grp2 mailbox row every ~33k cy; exits when all LB steps done.
    const int c = blk & 63;
    float a0 = 1.0f + (float)tid * 1e-6f, a1 = a0 + 0.25f;
    float a2 = a0 + 0.5f, a3 = a0 + 0.75f;
    const float mm = 0.99999988f, cc = 1e-7f;
    int run = 1;
    for (int it = 0; it < (1 << 17) && run; ++it) {
#pragma unroll
      for (int u = 0; u < 256; ++u) {
        a0 = __builtin_fmaf(a0, mm, cc); a1 = __builtin_fmaf(a1, mm, cc);
        a2 = __builtin_fmaf(a2, mm, cc); a3 = __builtin_fmaf(a3, mm, cc);
      }
      if ((it & 15) == 0) {
        int v = __hip_atomic_load(MB + (((2 * 64) + c) * 64 + (tid & 63)),
                                  __ATOMIC_RELAXED, __HIP_MEMORY_SCOPE_AGENT);
        if (__all(v >= Tn)) run = 0;
      }
    }
    asm volatile("" :: "v"(a0), "v"(a1), "v"(a2), "v"(a3));  // keep chains live
    return;
  }

  const bool isA = blk < 64;
  const int jt = blk & 63, jj = jt * 16;
  const int w = tid >> 6;                    // wave = K-slice = owner m-group
  const int lane = tid & 63;
  const int rl = lane & 15, kg = lane >> 4;

  __shared__ float cmb[4][4][64][20];        // stride 80B: conflict-free (r6)

  const int b = w * 16 + rl;                 // owner batch row (epilogue)
  const int j0 = jj + kg * 4;                // owner j base (epilogue)

  // ---- VGPR/AGPR-resident weights ----
  // v18 FIX (rule #20): constant trip counts per branch => SROA keeps the
  // arrays in the unified register file; no dynamic indexing anywhere.
  const float* Wi = isA ? wih0 : wih1;
  const float* Wh = isA ? whh0 : whh1;
  const float* bi = isA ? bih0 : bih1;
  const float* bh = isA ? bhh0 : bhh1;
  s8v wx[3][8], wh_[3][8];
#pragma unroll
  for (int g = 0; g < 3; ++g) {
    if (isA) {
#pragma unroll
      for (int kt = 0; kt < 4; ++kt)
        wx[g][kt] = pack8(Wi + (size_t)(g * 1024 + jj + rl) * INn + w * 128 + kt * 32 + kg * 8);
    } else {
#pragma unroll
      for (int kt = 0; kt < 8; ++kt)
        wx[g][kt] = pack8(Wi + (size_t)(g * 1024 + jj + rl) * Hn + w * 256 + kt * 32 + kg * 8);
    }
#pragma unroll
    for (int kt = 0; kt < 8; ++kt)
      wh_[g][kt] = pack8(Wh + (size_t)(g * 1024 + jj + rl) * Hn + w * 256 + kt * 32 + kg * 8);
  }
  const f4v bir = *(const f4v*)(bi + j0),        bhr = *(const f4v*)(bh + j0);
  const f4v biz = *(const f4v*)(bi + 1024 + j0), bhz = *(const f4v*)(bh + 1024 + j0);
  const f4v bin = *(const f4v*)(bi + 2048 + j0), bhn = *(const f4v*)(bh + 2048 + j0);

  // ---- register-resident fp32 hidden state (this thread's (b, j0..j0+3)) ----
  f4v hv = *(const f4v*)(h0in + (isA ? 0u : 65536u) + (size_t)b * Hn + j0);

  for (int s = 0; s < Tn; ++s) {
    // 1. LA: prefetch x fragments (plain cached loads, v4-proven) before spin
    s8v bx[4][4];
    if (isA) {
#pragma unroll
      for (int m = 0; m < 4; ++m)
#pragma unroll
        for (int kt = 0; kt < 4; ++kt)
          bx[m][kt] = *(const s8v*)(xb + ((size_t)(m * 16 + rl) * Tn + s) * INn + w * 128 + kt * 32 + kg * 8);
    }
    // 2. mailbox wait (wave0 only; private rows, sole reader per line)
    if (w == 0) {
      if (isA) mb_wait(MB, 0 * 64 + jt, s,     3 * 64 + jt, s - 255, lane);
      else     mb_wait(MB, 1 * 64 + jt, s + 1, 2 * 64 + jt, s,       lane);
    }
    __syncthreads();
    vmwait<0>();                             // clean baseline for counted pipe

    f4v acc[4][4];
#pragma unroll
    for (int m = 0; m < 4; ++m)
#pragma unroll
      for (int g = 0; g < 4; ++g) acc[m][g] = (f4v){0.f, 0.f, 0.f, 0.f};

    // deep-ring slots (no address reuse within 256+ steps => cache-safe)
    const unsigned short* hsrc = isA ? (h0r + (size_t)((s - 1) & 511) * 65536)
                                     : (h1r + (size_t)((s - 1) & 255) * 65536);
    const unsigned short* asrc = h0r + (size_t)(s & 511) * 65536;  // LB input h0[s]

    if (isA) {
      // 3a. x-GEMM from registers
#pragma unroll
      for (int kt = 0; kt < 4; ++kt) {
        s8v f4[4] = { bx[0][kt], bx[1][kt], bx[2][kt], bx[3][kt] };
        mfma3(acc, wx[0][kt], wx[1][kt], wx[2][kt], f4, 2);
      }
      // 3b. hidden stream, deep-pipelined
      stream_gemm_deep<3>(acc, wh_, hsrc, w, rl, kg);
    } else {
      // 3. a-stream then h-stream, each deep-pipelined (self-draining)
      stream_gemm_deep<2>(acc, wx, asrc, w, rl, kg);
      stream_gemm_deep<3>(acc, wh_, hsrc, w, rl, kg);
    }

    // 4. cross-wave K-combine (LDS)
#pragma unroll
    for (int d = 0; d < 4; ++d) if (d != w)
#pragma unroll
      for (int g = 0; g < 4; ++g) *(f4v*)&cmb[d][w][lane][g * 4] = acc[d][g];
    __syncthreads();
    f4v hsum[4];
#pragma unroll
    for (int g = 0; g < 4; ++g) {
      hsum[g] = acc[w][g];
#pragma unroll
      for (int src = 0; src < 4; ++src) if (src != w) hsum[g] += *(f4v*)&cmb[w][src][lane][g * 4];
    }

    // 5. epilogue: gates + zoneout, state stays in hv registers
    us4v hb4;
#pragma unroll
    for (int rr = 0; rr < 4; ++rr) {
      float hp = hv[rr];
      float rg = 1.f / (1.f + __expf(-(hsum[0][rr] + bir[rr] + bhr[rr])));
      float zg = 1.f / (1.f + __expf(-(hsum[1][rr] + biz[rr] + bhz[rr])));
      float narg = hsum[2][rr] + bin[rr] + rg * (hsum[3][rr] + bhn[rr]);
      float e2 = __expf(2.f * narg);
      float ng = 1.f - 2.f / (e2 + 1.f);
      float nv = (1.f - zg) * ng + zg * hp;
      hv[rr] = 0.1f * hp + 0.9f * nv;
    }
    hb4[0] = f2bf(hv[0]); hb4[1] = f2bf(hv[1]); hb4[2] = f2bf(hv[2]); hb4[3] = f2bf(hv[3]);

    // 6. broadcast bf16 h (write-through 8B atomics, issued FIRST), then out
    //    nt-stores; counted drain: wait only until st8c is acked.
    if (isA) {
      st8c(h0r + (size_t)(s & 511) * 65536 + jt * 1024 + b * 16 + kg * 4, hb4);
      if (s == Tn - 1)
        stnt16(out + 67108864u + (size_t)b * Hn + j0, hv);
      vmwait<0>();                           // st8c (+final store) acked
    } else {
      st8c(h1r + (size_t)(s & 255) * 65536 + jt * 1024 + b * 16 + kg * 4, hb4);
      stnt16(out + ((size_t)b * Tn + s) * Hn + j0, hv);
      if (s == Tn - 1) {
        stnt16(out + 67108864u + 65536u + (size_t)b * Hn + j0, hv);
        vmwait<0>();
      } else {
        vmwait<1>();                         // st8c acked; out-store off-chain
      }
    }
    __syncthreads();
    // 7. flag fan-out: wave0's 64 lanes scatter (s+1) to the 64 consumer
    //    rows of each served group (plain relaxed stores, no RMW).
    if (tid < 64) {
      const int g1 = isA ? 0 : 2, g2 = isA ? 1 : 3;
      __hip_atomic_store(MB + ((g1 * 64 + tid) * 64 + jt), s + 1,
                         __ATOMIC_RELAXED, __HIP_MEMORY_SCOPE_AGENT);
      __hip_atomic_store(MB + ((g2 * 64 + tid) * 64 + jt), s + 1,
                         __ATOMIC_RELAXED, __HIP_MEMORY_SCOPE_AGENT);
    }
  }
}

extern "C" void kernel_launch(void* const* d_in, const int* in_sizes, int n_in,
                              void* d_out, int out_size, void* d_ws, size_t ws_size,
                              hipStream_t stream) {
  (void)in_sizes; (void)n_in; (void)out_size; (void)ws_size;
  const float* x    = (const float*)d_in[0];
  const float* h0in = (const float*)d_in[1];
  const float* wih0 = (const float*)d_in[2];
  const float* whh0 = (const float*)d_in[3];
  const float* bih0 = (const float*)d_in[4];
  const float* bhh0 = (const float*)d_in[5];
  const float* bih1_ = (const float*)d_in[8];
  const float* wih1 = (const float*)d_in[6];
  const float* whh1 = (const float*)d_in[7];
  const float* bhh1 = (const float*)d_in[9];
  float* out = (float*)d_out;
  char* ws = (char*)d_ws;

  cvt_bf16_kernel<<<2048, 256, 0, stream>>>(x, (unsigned short*)(ws + WS_XB), 33554432 / 4);
  init_all<<<528, 256, 0, stream>>>(h0in, ws);
  gru_persist<<<dim3(256), dim3(256), 0, stream>>>(
      h0in, wih0, whh0, bih0, bhh0, wih1, whh1, bih1_, bhh1, out, ws);
}